// Round 5
// baseline (343.334 us; speedup 1.0000x reference)
//
#include <hip/hip_runtime.h>
#include <hip/hip_bf16.h>

typedef __attribute__((ext_vector_type(8))) short bf16x8;
typedef __attribute__((ext_vector_type(4))) float f32x4;

#define NTILE 4      // tiles per block
#define BM    32     // rows per tile

#define MFMA(a, b, c) __builtin_amdgcn_mfma_f32_16x16x32_bf16((a), (b), (c), 0, 0, 0)

static __device__ __forceinline__ short f2bf(float x) {
  union { __hip_bfloat16 h; short s; } u; u.h = __float2bfloat16(x); return u.s;
}
static __device__ __forceinline__ short4 pk4(float4 v) {
  short4 s; s.x = f2bf(v.x); s.y = f2bf(v.y); s.z = f2bf(v.z); s.w = f2bf(v.w);
  return s;
}
static __device__ __forceinline__ bf16x8 pk8(float4 a, float4 b) {
  bf16x8 r;
  r[0] = f2bf(a.x); r[1] = f2bf(a.y); r[2] = f2bf(a.z); r[3] = f2bf(a.w);
  r[4] = f2bf(b.x); r[5] = f2bf(b.y); r[6] = f2bf(b.z); r[7] = f2bf(b.w);
  return r;
}

typedef __attribute__((address_space(3))) unsigned as3_u32;
typedef __attribute__((address_space(1))) unsigned as1_u32;
static __device__ __forceinline__ void gload16(const void* g, void* l) {
  __builtin_amdgcn_global_load_lds((const as1_u32*)g, (as3_u32*)l, 16, 0, 0);
}

// ---------------- prepass: bf16 tables + transposed weights ----------------
#define N_NODES_EL 3200000   // 50000*64
#define N_W1T      57344     // 256*224
#define N_W2T      16384     // 64*256
#define N_GLOB     256       // 8*32

__global__ void prep(const float* __restrict__ nodes,
                     const float* __restrict__ glob,
                     const float* __restrict__ W1,
                     const float* __restrict__ W2,
                     short* __restrict__ nodesBF,
                     short* __restrict__ globBF,
                     short* __restrict__ W1T,
                     short* __restrict__ W2T) {
  int i = blockIdx.x * 256 + threadIdx.x;
  if (i < N_NODES_EL) { nodesBF[i] = f2bf(nodes[i]); return; }
  i -= N_NODES_EL;
  if (i < N_W1T) {  // W1T[n][k] = W1[k][n], W1 is [224][256]
    int n = i / 224, k = i % 224;
    W1T[i] = f2bf(W1[k * 256 + n]);
    return;
  }
  i -= N_W1T;
  if (i < N_W2T) {  // W2T[n][k] = W2[k][n], W2 is [256][64]
    int n = i >> 8, k = i & 255;
    W2T[i] = f2bf(W2[k * 64 + n]);
    return;
  }
  i -= N_W2T;
  if (i < N_GLOB) globBF[i] = f2bf(glob[i]);
}

// ---------------- main fused kernel ----------------
// LDS layout (bytes), total 53,248:
//  E (f32)  [2][32 rows][64 f32]  : p*8192          (row 256B, chunk-swz by r&7)
//  R (bf16) [2][32][64]           : 16384 + p*4096  (row 128B, chunk-swz by r&7)
//  S (bf16) [2][32][64]           : 24576 + p*4096
//  G (bf16) [2][32][32]           : 32768 + p*2048  (row 64B, chunk-swz by r&3)
//  H (bf16) [32][256]             : 36864           (row 512B, chunk-swz by r&7)

__global__ __launch_bounds__(512, 4) void edge_mlp(
    const float* __restrict__ edges,
    const int* __restrict__ recv,
    const int* __restrict__ send,
    const int* __restrict__ egi,
    const short* __restrict__ nodesBF,
    const short* __restrict__ globBF,
    const short* __restrict__ W1T,
    const short* __restrict__ W2T,
    const float* __restrict__ b1,
    const float* __restrict__ b2,
    float* __restrict__ out)
{
  __shared__ __align__(16) char LDS[53248];

  const int t    = threadIdx.x;
  const int lane = t & 63;
  const int w    = t >> 6;        // wave 0..7
  const int l15  = lane & 15;
  const int g4   = lane >> 4;     // 0..3

  const long base_e = (long)blockIdx.x * (NTILE * BM);

  // ---- prologue: loop-invariant W1 fragments + biases ----
  bf16x8 w1f[2][7];
  #pragma unroll
  for (int ntp = 0; ntp < 2; ++ntp)
    #pragma unroll
    for (int k0 = 0; k0 < 7; ++k0)
      w1f[ntp][k0] = *reinterpret_cast<const bf16x8*>(
          &W1T[((w * 2 + ntp) * 16 + l15) * 224 + k0 * 32 + g4 * 8]);
  float4 b1v[2];
  b1v[0] = *reinterpret_cast<const float4*>(&b1[(w * 2 + 0) * 16 + g4 * 4]);
  b1v[1] = *reinterpret_cast<const float4*>(&b1[(w * 2 + 1) * 16 + g4 * 4]);
  const float4 b2v = *reinterpret_cast<const float4*>(&b2[(w & 3) * 16 + g4 * 4]);

  // per-wave staging geometry (wave-uniform)
  const int erow = w * 4 + (lane >> 4);            // E row this lane stages
  const int echk = (lane & 15) ^ (erow & 7);       // source chunk (16B) swizzle
  const int nrow = (w & 3) * 8 + (lane >> 3);      // R/S row
  const int nchk = (lane & 7) ^ (lane >> 3);
  const int grow = (w & 1) * 16 + (lane >> 2);     // G row
  const int gchk = (lane & 3) ^ (grow & 3);

  char* const ldsE = LDS;
  char* const ldsR = LDS + 16384;
  char* const ldsS = LDS + 24576;
  char* const ldsG = LDS + 32768;
  char* const ldsH = LDS + 36864;

  // issue gather for tile 0 into buf p=0
  {
    const long e0 = base_e;
    int idxRS = (w < 4) ? recv[e0 + nrow] : send[e0 + nrow];
    int idxG  = egi[e0 + grow];
    asm volatile("s_waitcnt vmcnt(0)" ::: "memory");
    gload16(edges + (e0 + erow) * 64 + echk * 4, ldsE + w * 1024 + lane * 16);
    gload16(nodesBF + (size_t)idxRS * 64 + nchk * 8,
            (w < 4 ? ldsR : ldsS) + (w & 3) * 1024 + lane * 16);
    gload16(globBF + (size_t)idxG * 32 + gchk * 8, ldsG + (w & 1) * 1024 + lane * 16);
  }

  #pragma unroll
  for (int tt = 0; tt < NTILE; ++tt) {
    const int p = tt & 1;
    const long e0 = base_e + tt * BM;
    char* const eb = ldsE + p * 8192;
    char* const rb = ldsR + p * 4096;
    char* const sb = ldsS + p * 4096;
    char* const gb = ldsG + p * 2048;

    // ---- top: idx(t+1), drain g(t), issue g(t+1), join ----
    if (tt < NTILE - 1) {
      const long e1 = e0 + BM;
      int idxRS = (w < 4) ? recv[e1 + nrow] : send[e1 + nrow];
      int idxG  = egi[e1 + grow];
      asm volatile("s_waitcnt vmcnt(0)" ::: "memory");   // g(t) done; queue empty
      char* const ebn = ldsE + (p ^ 1) * 8192;
      char* const rbn = ldsR + (p ^ 1) * 4096;
      char* const sbn = ldsS + (p ^ 1) * 4096;
      char* const gbn = ldsG + (p ^ 1) * 2048;
      gload16(edges + (e1 + erow) * 64 + echk * 4, ebn + w * 1024 + lane * 16);
      gload16(nodesBF + (size_t)idxRS * 64 + nchk * 8,
              (w < 4 ? rbn : sbn) + (w & 3) * 1024 + lane * 16);
      gload16(globBF + (size_t)idxG * 32 + gchk * 8, gbn + (w & 1) * 1024 + lane * 16);
    } else {
      asm volatile("s_waitcnt vmcnt(0)" ::: "memory");
    }
    asm volatile("s_barrier" ::: "memory");   // all waves' g(t) staged

    // ---- layer 1: D[n][m] = W1T-frag x X-frag; wave owns n [w*32, w*32+32) ----
    f32x4 acc[2][2];
    acc[0][0] = f32x4{0.f,0.f,0.f,0.f}; acc[0][1] = f32x4{0.f,0.f,0.f,0.f};
    acc[1][0] = f32x4{0.f,0.f,0.f,0.f}; acc[1][1] = f32x4{0.f,0.f,0.f,0.f};

    __builtin_amdgcn_s_setprio(1);
    // k0 = 0,1 : E (f32 in LDS -> cvt)
    #pragma unroll
    for (int k0 = 0; k0 < 2; ++k0)
      #pragma unroll
      for (int mi = 0; mi < 2; ++mi) {
        const int m = mi * 16 + l15;
        const int c = k0 * 8 + g4 * 2;   // f32 16B-chunk index
        float4 ea = *reinterpret_cast<const float4*>(eb + m * 256 + ((c ^ (m & 7)) << 4));
        float4 eb2 = *reinterpret_cast<const float4*>(eb + m * 256 + (((c + 1) ^ (m & 7)) << 4));
        bf16x8 xa = pk8(ea, eb2);
        acc[mi][0] = MFMA(w1f[0][k0], xa, acc[mi][0]);
        acc[mi][1] = MFMA(w1f[1][k0], xa, acc[mi][1]);
      }
    // k0 = 2,3 : R
    #pragma unroll
    for (int k0 = 2; k0 < 4; ++k0)
      #pragma unroll
      for (int mi = 0; mi < 2; ++mi) {
        const int m = mi * 16 + l15;
        const int c = (k0 - 2) * 4 + g4;  // bf16 16B-chunk in R row
        bf16x8 xa = *reinterpret_cast<const bf16x8*>(rb + m * 128 + ((c ^ (m & 7)) << 4));
        acc[mi][0] = MFMA(w1f[0][k0], xa, acc[mi][0]);
        acc[mi][1] = MFMA(w1f[1][k0], xa, acc[mi][1]);
      }
    // k0 = 4,5 : S
    #pragma unroll
    for (int k0 = 4; k0 < 6; ++k0)
      #pragma unroll
      for (int mi = 0; mi < 2; ++mi) {
        const int m = mi * 16 + l15;
        const int c = (k0 - 4) * 4 + g4;
        bf16x8 xa = *reinterpret_cast<const bf16x8*>(sb + m * 128 + ((c ^ (m & 7)) << 4));
        acc[mi][0] = MFMA(w1f[0][k0], xa, acc[mi][0]);
        acc[mi][1] = MFMA(w1f[1][k0], xa, acc[mi][1]);
      }
    // k0 = 6 : G
    #pragma unroll
    for (int mi = 0; mi < 2; ++mi) {
      const int m = mi * 16 + l15;
      bf16x8 xa = *reinterpret_cast<const bf16x8*>(gb + m * 64 + ((g4 ^ (m & 3)) << 4));
      acc[mi][0] = MFMA(w1f[0][6], xa, acc[mi][0]);
      acc[mi][1] = MFMA(w1f[1][6], xa, acc[mi][1]);
    }
    __builtin_amdgcn_s_setprio(0);

    // ---- H epilogue: relu+bias -> bf16 H in LDS (swizzled) ----
    #pragma unroll
    for (int ntp = 0; ntp < 2; ++ntp) {
      const int n = w * 32 + ntp * 16 + g4 * 4;
      #pragma unroll
      for (int mi = 0; mi < 2; ++mi) {
        const int m = mi * 16 + l15;
        float4 v;
        v.x = acc[mi][ntp][0] + b1v[ntp].x;
        v.y = acc[mi][ntp][1] + b1v[ntp].y;
        v.z = acc[mi][ntp][2] + b1v[ntp].z;
        v.w = acc[mi][ntp][3] + b1v[ntp].w;
        v.x = v.x > 0.f ? v.x : 0.f;
        v.y = v.y > 0.f ? v.y : 0.f;
        v.z = v.z > 0.f ? v.z : 0.f;
        v.w = v.w > 0.f ? v.w : 0.f;
        *reinterpret_cast<short4*>(
            ldsH + m * 512 + (((n >> 3) ^ (m & 7)) << 4) + (n & 7) * 2) = pk4(v);
      }
    }
    asm volatile("s_waitcnt lgkmcnt(0)\ns_barrier" ::: "memory");  // H visible; X(t) free

    // ---- layer 2: D[oc][m]; wave -> oc-tile w&3, m-tile w>>2 ----
    const int oc = w & 3;
    const int m2 = (w >> 2) * 16 + l15;
    f32x4 acc2 = f32x4{0.f,0.f,0.f,0.f};
    __builtin_amdgcn_s_setprio(1);
    #pragma unroll
    for (int k0 = 0; k0 < 8; ++k0) {
      bf16x8 wf = *reinterpret_cast<const bf16x8*>(
          &W2T[(oc * 16 + l15) * 256 + k0 * 32 + g4 * 8]);
      const int c = k0 * 4 + g4;
      bf16x8 hb = *reinterpret_cast<const bf16x8*>(
          ldsH + m2 * 512 + ((c ^ (m2 & 7)) << 4));
      acc2 = MFMA(wf, hb, acc2);
    }
    __builtin_amdgcn_s_setprio(0);

    // ---- store ----
    {
      float4 o;
      o.x = acc2[0] + b2v.x;
      o.y = acc2[1] + b2v.y;
      o.z = acc2[2] + b2v.z;
      o.w = acc2[3] + b2v.w;
      *reinterpret_cast<float4*>(&out[(size_t)(e0 + m2) * 64 + oc * 16 + g4 * 4]) = o;
    }
  }
}

extern "C" void kernel_launch(void* const* d_in, const int* in_sizes, int n_in,
                              void* d_out, int out_size, void* d_ws, size_t ws_size,
                              hipStream_t stream) {
  (void)in_sizes; (void)n_in; (void)out_size; (void)ws_size;
  const float* edges = (const float*)d_in[0];
  const float* nodes = (const float*)d_in[1];
  const float* glob  = (const float*)d_in[2];
  const int*   recv  = (const int*)d_in[3];
  const int*   send  = (const int*)d_in[4];
  const int*   egi   = (const int*)d_in[5];
  const float* W1    = (const float*)d_in[6];
  const float* b1    = (const float*)d_in[7];
  const float* W2    = (const float*)d_in[8];
  const float* b2    = (const float*)d_in[9];
  float* out = (float*)d_out;

  short* nodesBF = (short*)d_ws;                       // 3,200,000 *2B
  short* W1T     = nodesBF + N_NODES_EL;               // 57,344
  short* W2T     = W1T + N_W1T;                        // 16,384
  short* globBF  = W2T + N_W2T;                        // 256

  const int prep_total = N_NODES_EL + N_W1T + N_W2T + N_GLOB;
  prep<<<(prep_total + 255) / 256, 256, 0, stream>>>(nodes, glob, W1, W2,
                                                     nodesBF, globBF, W1T, W2T);
  edge_mlp<<<800000 / (NTILE * BM), 512, 0, stream>>>(
      edges, recv, send, egi, nodesBF, globBF, W1T, W2T, b1, b2, out);
}